// Round 2
// baseline (482.779 us; speedup 1.0000x reference)
//
#include <hip/hip_runtime.h>
#include <hip/hip_fp16.h>
#include <cstdint>
#include <cstring>

// VQR circuit simulator: 16 qubits, B=512, 4 layers.
// CNOTs are GF(2) index-relabeling bookkeeping. Fused 1q gates (SU(2)) are
// XOR-mask pair rotations. Host schedules gates into 2 window passes;
// within a pass, gates are grouped into MEGA-BUNDLES: up to 4 gates define
// a rank-4 coset basis, and any subsequent gate whose mask lies IN THE SPAN
// is applied in-register (4-bit pair mask mt, 15-case uniform switch) with
// no LDS round-trip. Amplitudes fp16 end-to-end. Inner math is SoA-packed
// (re/im in separate half2 regs, 2 amps per reg): every v_pk_fma_f16 operand
// is a plain register -- no swizzles, no fneg, no modifier-folding reliance.
// Runtime parity signs are 3-4 v_xor per 2 pairs from host-baked masks.

struct BundleB {
    uint16_t voff[16];   // coset offsets (local 12-bit index space)
    uint8_t  piv[4];     // pivot bit positions, ASCENDING (rep expansion)
    uint8_t  g0, ng;     // gate range [g0, g0+ng) in the pass gate list
    uint8_t  pad[2];
};

struct PassMeta {
    int32_t  nbundles;
    BundleB  bd[12];
    uint32_t ginfo[48];      // row(0..15) | nl(16..19) | gidx(20..27) | mt(28..31)
    uint32_t maskS[48][8];   // per-gate per-reg sign masks (bit15=lo elem, bit31=hi elem)
    uint32_t measS[8];       // measurement voff-parity bits (bit0=lo, bit1=hi) per reg
    uint8_t  gap[4];         // non-local bit positions, ASCENDING (all >=8)
    uint8_t  nlw[4];         // chunk bit k -> wire
    uint8_t  wire_of_bit[12];// packed LDS bit -> wire (product-state init)
    uint16_t meas_row;       // measurement parity mask (local bits)
    uint8_t  meas_nl;        // measurement parity mask (chunk bits)
    uint8_t  pad;
};

typedef _Float16 h2 __attribute__((ext_vector_type(2)));

__device__ __forceinline__ float2 cmul2(float2 a, float2 b) {
    return make_float2(a.x * b.x - a.y * b.y, a.x * b.y + a.y * b.x);
}
__device__ __forceinline__ h2 pkfma(h2 a, h2 b, h2 c) {
    return __builtin_bit_cast(h2, __hfma2(__builtin_bit_cast(__half2, a),
                                          __builtin_bit_cast(__half2, b),
                                          __builtin_bit_cast(__half2, c)));
}
__device__ __forceinline__ h2 h2x(h2 a, unsigned m) {
    return __builtin_bit_cast(h2, __builtin_bit_cast(unsigned, a) ^ m);
}
__device__ __forceinline__ h2 swap16h(h2 a) {
    return __builtin_bit_cast(h2,
        __builtin_rotateleft32(__builtin_bit_cast(unsigned, a), 16));
}
__device__ __forceinline__ h2 bch2(unsigned u) { return __builtin_bit_cast(h2, u); }
__device__ __forceinline__ unsigned bcu(h2 a) { return __builtin_bit_cast(unsigned, a); }
__device__ __forceinline__ float xorf(float a, unsigned s) {
    return __uint_as_float(__float_as_uint(a) ^ s);
}
__device__ __forceinline__ unsigned pkh2(float lo, float hi) {
    h2 v; v.x = (_Float16)lo; v.y = (_Float16)hi;
    return __builtin_bit_cast(unsigned, v);
}

// Fused U = Rz(t2)Ry(t1)Rz(t0)Rx(enc), enc = 2*atan(x).
// Emit packed-h2 quad: [ar,ar] [ai,ai] [br,br] [bi,bi]   (plain, no signs baked)
__global__ __launch_bounds__(512)
void precompute_kernel(const float* __restrict__ X, const float* __restrict__ Wt,
                       const float* __restrict__ Bs, uint4* __restrict__ Ug,
                       float* __restrict__ out)
{
    int id = blockIdx.x * 512 + threadIdx.x;
    if (id >= 512 * 64) return;
    int b = id >> 6, lw = id & 63, l = lw >> 4, w = lw & 15;
    float x  = X[b * 16 + w];
    float ce = 1.0f / sqrtf(1.0f + x * x);
    float se = x * ce;
    float t0 = 0.5f * Wt[(l * 16 + w) * 3 + 0];
    float t1 = 0.5f * Wt[(l * 16 + w) * 3 + 1];
    float t2 = 0.5f * Wt[(l * 16 + w) * 3 + 2];
    float c1 = cosf(t1), s1 = sinf(t1);
    float ca = cosf(t0 + t2), sa = sinf(t0 + t2);
    float cb = cosf(t2 - t0), sb = sinf(t2 - t0);
    float2 W00 = make_float2( c1 * ca, -c1 * sa);
    float2 W01 = make_float2(-s1 * cb,  s1 * sb);
    float2 a  = make_float2(W00.x * ce + W01.y * se, W00.y * ce - W01.x * se);
    float2 bb = make_float2(W00.y * se + W01.x * ce, -W00.x * se + W01.y * ce);
    uint4 o;
    o.x = pkh2(a.x,  a.x);    // AR2
    o.y = pkh2(a.y,  a.y);    // AI2
    o.z = pkh2(bb.x, bb.x);   // BR2
    o.w = pkh2(bb.y, bb.y);   // BI2
    Ug[id] = o;
    if (lw == 0) out[b] = Bs[0];
}

// Apply one gate with compile-time pair-mask M to SoA registers.
// RE[k]/IM[k] hold amps (2k, 2k+1) of the thread's 16-amp coset.
// Formulas (p,q pair; s = runtime sign; tai=s*ai, tbr=s*br):
//   npr = ar*pr - tai*pi + tbr*qr - bi*qi
//   npi = ar*pi + tai*pr + tbr*qi + bi*qr
//   nqr = -tbr*pr - bi*pi + ar*qr + tai*qi
//   nqi = -tbr*pi + bi*pr + ar*qi - tai*qr
// M==1 uses the symmetric per-element form (valid since parity(D&R)=1 so
// partner's sign is always the opposite).
template <int M>
__device__ __forceinline__ void apply_gate(h2 (&RE)[8], h2 (&IM)[8],
    h2 AR2, h2 AIs, h2 BRs, h2 BI2, h2 BIn, const uint32_t (&mk)[8])
{
    if constexpr (M == 1) {
        #pragma unroll
        for (int k = 0; k < 8; ++k) {
            h2 QRE = swap16h(RE[k]), QIM = swap16h(IM[k]);
            unsigned m = mk[k];
            h2 TAI = h2x(AIs, m), TAIn = h2x(TAI, 0x80008000u);
            h2 TBR = h2x(BRs, m);
            h2 t0 = pkfma(TBR, QRE, BIn * QIM);
            h2 nre = pkfma(AR2, RE[k], pkfma(TAIn, IM[k], t0));
            h2 t1 = pkfma(TBR, QIM, BI2 * QRE);
            h2 nim = pkfma(AR2, IM[k], pkfma(TAI, RE[k], t1));
            RE[k] = nre; IM[k] = nim;
        }
    } else {
        constexpr int MS = 31 - __builtin_clz((unsigned)M);  // msb in t-space
        constexpr int mp = M >> 1;
        constexpr bool crossed = (M & 1);
        #pragma unroll
        for (int k = 0; k < 8; ++k) {
            if (k & (1 << (MS - 1))) continue;   // compile-time prune: P-regs only
            const int kq = k ^ mp;
            h2 QRE, QIM;
            if constexpr (crossed) { QRE = swap16h(RE[kq]); QIM = swap16h(IM[kq]); }
            else                   { QRE = RE[kq];          QIM = IM[kq]; }
            unsigned m = mk[k];
            h2 TAI = h2x(AIs, m), TAIn = h2x(TAI, 0x80008000u);
            h2 TBR = h2x(BRs, m), TBRn = h2x(TBR, 0x80008000u);
            h2 PRE = RE[k], PIM = IM[k];
            h2 npre = pkfma(AR2, PRE, pkfma(TAIn, PIM, pkfma(TBR, QRE, BIn * QIM)));
            h2 npim = pkfma(AR2, PIM, pkfma(TAI,  PRE, pkfma(TBR, QIM, BI2 * QRE)));
            h2 nqre = pkfma(TBRn, PRE, pkfma(BIn, PIM, pkfma(AR2, QRE, TAI  * QIM)));
            h2 nqim = pkfma(TBRn, PIM, pkfma(BI2, PRE, pkfma(AR2, QIM, TAIn * QRE)));
            RE[k] = npre; IM[k] = npim;
            if constexpr (crossed) { RE[kq] = swap16h(nqre); IM[kq] = swap16h(nqim); }
            else                   { RE[kq] = nqre;          IM[kq] = nqim; }
        }
    }
}

// MODE 0: generate product state + gates + store (fp16)
// MODE 1: load + gates + store (in-place, fp16)
// MODE 2: load + gates + measurement reduce (no store)
template <int MODE>
__global__ __launch_bounds__(256, 6)
void pass_kernel(const uint4* __restrict__ Ug, unsigned* __restrict__ state,
                 float* __restrict__ out, PassMeta meta)
{
    __shared__ __align__(16) h2 amp[4096];   // 16 KiB (one half2 per amp)
    __shared__ uint4 coef[64];               // packed-h2 gate quads (1 KiB)
    const int tid = threadIdx.x;
    const int bb  = blockIdx.x >> 4;
    const unsigned c = blockIdx.x & 15u;
    const size_t base = (size_t)bb << 16;
    if (tid < 64) coef[tid] = Ug[(size_t)bb * 64 + tid];

    auto expand = [&](unsigned x) -> unsigned {   // gaps ascending, all >= 8
        #pragma unroll
        for (int k = 0; k < 4; ++k) {
            unsigned g = meta.gap[k];
            x = ((x >> g) << (g + 1)) | (x & ((1u << g) - 1u)) | (((c >> k) & 1u) << g);
        }
        return x;
    };

    if constexpr (MODE == 0) {
        __syncthreads();   // coef ready
        if (tid == 0) {
            float2 kv = make_float2(1.f, 0.f);
            for (int t = 0; t < 4; ++t) {
                uint4 u = coef[meta.nlw[t]];
                float ar = (float)bch2(u.x).x, ai = (float)bch2(u.y).x;
                float br = (float)bch2(u.z).x, bi = (float)bch2(u.w).x;
                float2 col = ((c >> t) & 1u) ? make_float2(-br, bi)
                                             : make_float2(ar, ai);
                kv = cmul2(kv, col);
            }
            h2 k2; k2.x = (_Float16)kv.x; k2.y = (_Float16)kv.y;
            amp[0] = k2;
        }
        __syncthreads();
        for (int s = 0; s < 12; ++s) {
            const int n = 1 << s;
            uint4 cf = coef[meta.wire_of_bit[s]];
            const h2 AR2  = bch2(cf.x);
            const h2 AIpm = h2x(bch2(cf.y), 0x00008000u);  // [-ai, ai]
            const h2 BRn  = h2x(bch2(cf.z), 0x80008000u);  // [-br,-br]
            const h2 BIpm = h2x(bch2(cf.w), 0x00008000u);  // [-bi, bi]
            for (int i = tid; i < n; i += 256) {
                h2 a = amp[i];
                h2 sw = swap16h(a);
                amp[i + n] = pkfma(BRn, a, BIpm * sw);   // a * (-br, bi)
                amp[i]     = pkfma(AR2, a, AIpm * sw);   // a * ( ar, ai)
            }
            __syncthreads();
        }
    } else {
        #pragma unroll
        for (int it = 0; it < 4; ++it) {
            unsigned u = (unsigned)(tid + it * 256) * 4u;
            unsigned a = expand(u);
            uint4 v = *reinterpret_cast<const uint4*>(state + base + a);
            *reinterpret_cast<uint4*>(&amp[u]) = v;   // 4 amps = 16 B, b128
        }
        __syncthreads();   // also covers coef staging
    }

    for (int ci = 0; ci < meta.nbundles; ++ci) {
        const BundleB& B = meta.bd[ci];
        unsigned r = (unsigned)tid;
        #pragma unroll
        for (int k = 0; k < 4; ++k) {
            unsigned p = B.piv[k];
            r = ((r >> p) << (p + 1)) | (r & ((1u << p) - 1u));
        }
        const unsigned rb = r << 2;   // byte offset; xor with voff<<2 (scalar)
        h2 RE[8], IM[8];
        #pragma unroll
        for (int k = 0; k < 8; ++k) {
            unsigned a0 = rb ^ ((unsigned)B.voff[2 * k] << 2);
            unsigned a1 = rb ^ ((unsigned)B.voff[2 * k + 1] << 2);
            unsigned u0 = *(const unsigned*)((const char*)amp + a0);
            unsigned u1 = *(const unsigned*)((const char*)amp + a1);
            RE[k] = bch2(__builtin_amdgcn_perm(u1, u0, 0x05040100u));
            IM[k] = bch2(__builtin_amdgcn_perm(u1, u0, 0x07060302u));
        }
        const int g0 = B.g0, ng = B.ng;
        for (int gi = 0; gi < ng; ++gi) {
            const uint32_t info = meta.ginfo[g0 + gi];
            const uint4 cf = coef[(info >> 20) & 63u];
            const h2 AR2 = bch2(cf.x), AI2 = bch2(cf.y);
            const h2 BR2 = bch2(cf.z), BI2 = bch2(cf.w);
            const unsigned row = info & 0xFFFFu;
            const unsigned nl  = (info >> 16) & 15u;
            const unsigned par = ((unsigned)__popc(r & row) +
                                  (unsigned)__popc(nl & c)) & 1u;
            const unsigned gm = par ? 0x80008000u : 0u;
            const h2 AIs = h2x(AI2, gm);
            const h2 BRs = h2x(BR2, gm);
            const h2 BIn = h2x(BI2, 0x80008000u);
            const uint32_t (&mk)[8] = meta.maskS[g0 + gi];
            switch (info >> 28) {
                case  1: apply_gate< 1>(RE, IM, AR2, AIs, BRs, BI2, BIn, mk); break;
                case  2: apply_gate< 2>(RE, IM, AR2, AIs, BRs, BI2, BIn, mk); break;
                case  3: apply_gate< 3>(RE, IM, AR2, AIs, BRs, BI2, BIn, mk); break;
                case  4: apply_gate< 4>(RE, IM, AR2, AIs, BRs, BI2, BIn, mk); break;
                case  5: apply_gate< 5>(RE, IM, AR2, AIs, BRs, BI2, BIn, mk); break;
                case  6: apply_gate< 6>(RE, IM, AR2, AIs, BRs, BI2, BIn, mk); break;
                case  7: apply_gate< 7>(RE, IM, AR2, AIs, BRs, BI2, BIn, mk); break;
                case  8: apply_gate< 8>(RE, IM, AR2, AIs, BRs, BI2, BIn, mk); break;
                case  9: apply_gate< 9>(RE, IM, AR2, AIs, BRs, BI2, BIn, mk); break;
                case 10: apply_gate<10>(RE, IM, AR2, AIs, BRs, BI2, BIn, mk); break;
                case 11: apply_gate<11>(RE, IM, AR2, AIs, BRs, BI2, BIn, mk); break;
                case 12: apply_gate<12>(RE, IM, AR2, AIs, BRs, BI2, BIn, mk); break;
                case 13: apply_gate<13>(RE, IM, AR2, AIs, BRs, BI2, BIn, mk); break;
                case 14: apply_gate<14>(RE, IM, AR2, AIs, BRs, BI2, BIn, mk); break;
                case 15: apply_gate<15>(RE, IM, AR2, AIs, BRs, BI2, BIn, mk); break;
                default: break;
            }
        }
        if (MODE == 2 && ci == meta.nbundles - 1) {
            // measure directly from registers (f32 squares, skip LDS round-trip)
            float acc = 0.f;
            const unsigned mrp = ((((unsigned)__popc(r & (unsigned)meta.meas_row)
                                  + (unsigned)__popc((unsigned)meta.meas_nl & c)) & 1u)) << 31;
            #pragma unroll
            for (int k = 0; k < 8; ++k) {
                float rlo = (float)RE[k].x, rhi = (float)RE[k].y;
                float ilo = (float)IM[k].x, ihi = (float)IM[k].y;
                float plo = __builtin_fmaf(rlo, rlo, ilo * ilo);
                float phi = __builtin_fmaf(rhi, rhi, ihi * ihi);
                unsigned s2 = meta.measS[k];
                acc += xorf(plo, mrp ^ ((s2 & 1u) << 31));
                acc += xorf(phi, mrp ^ ((s2 & 2u) << 30));
            }
            for (int off = 32; off > 0; off >>= 1) acc += __shfl_down(acc, off, 64);
            if ((tid & 63) == 0) atomicAdd(&out[bb], acc);
            return;
        }
        #pragma unroll
        for (int k = 0; k < 8; ++k) {
            unsigned a0 = rb ^ ((unsigned)B.voff[2 * k] << 2);
            unsigned a1 = rb ^ ((unsigned)B.voff[2 * k + 1] << 2);
            unsigned re = bcu(RE[k]), im = bcu(IM[k]);
            *(unsigned*)((char*)amp + a0) = __builtin_amdgcn_perm(im, re, 0x05040100u);
            *(unsigned*)((char*)amp + a1) = __builtin_amdgcn_perm(im, re, 0x07060302u);
        }
        __syncthreads();
    }

    if constexpr (MODE == 2) {
        // fallback (only if nbundles==0): measure from LDS
        float acc = 0.f;
        const unsigned mcp = (unsigned)(__popc((unsigned)meta.meas_nl & c) & 1);
        for (int k = 0; k < 16; ++k) {
            unsigned u = (unsigned)(tid + k * 256);
            h2 a = amp[u];
            float vr = (float)a.x, vi = (float)a.y;
            float pr = __builtin_fmaf(vr, vr, vi * vi);
            acc += (((unsigned)__popc(u & (unsigned)meta.meas_row) & 1u) ^ mcp)
                 ? -pr : pr;
        }
        for (int off = 32; off > 0; off >>= 1) acc += __shfl_down(acc, off, 64);
        if ((tid & 63) == 0) atomicAdd(&out[bb], acc);
    } else {
        #pragma unroll
        for (int it = 0; it < 4; ++it) {
            unsigned u = (unsigned)(tid + it * 256) * 4u;
            unsigned ad = expand(u);
            uint4 v = *reinterpret_cast<const uint4*>(&amp[u]);
            *reinterpret_cast<uint4*>(state + base + ad) = v;
        }
    }
}

extern "C" void kernel_launch(void* const* d_in, const int* in_sizes, int n_in,
                              void* d_out, int out_size, void* d_ws, size_t ws_size,
                              hipStream_t stream)
{
    const float* X  = (const float*)d_in[0];
    const float* Wt = (const float*)d_in[1];
    const float* Bs = (const float*)d_in[2];
    float* out = (float*)d_out;

    const size_t UG_BYTES = (size_t)512 * 64 * sizeof(uint4);  // 512 KiB
    uint4*    Ug    = (uint4*)d_ws;
    unsigned* state = (unsigned*)((char*)d_ws + UG_BYTES);
    size_t avail = ws_size > UG_BYTES ? ws_size - UG_BYTES : 0;
    int group = 1;   // fp16 state: 256 KiB per batch element
    while (group < 512 && (size_t)(group * 2) * 262144ull <= avail)
        group <<= 1;
    const int ngroups = 512 / group;

    // ---- GF(2) bookkeeping (sequential CNOT ring, matches reference) ----
    uint16_t D[16], R[16];
    for (int w = 0; w < 16; ++w) { D[w] = R[w] = (uint16_t)(1u << w); }
    struct G { uint16_t D, R; uint8_t gidx; bool kept; bool sched; };
    G gl[48]; int ng = 0;
    for (int l = 1; l <= 3; ++l) {
        for (int w = 0; w < 16; ++w) { int t = (w + 1) & 15; D[w] ^= D[t]; R[t] ^= R[w]; }
        for (int w = 0; w < 16; ++w)
            gl[ng++] = G{D[w], R[w], (uint8_t)(l * 16 + w), true, false};
    }
    for (int w = 0; w < 16; ++w) { int t = (w + 1) & 15; D[w] ^= D[t]; R[t] ^= R[w]; }
    const uint16_t Rmeas = R[0];

    // Backward prune
    {
        uint16_t keptD[49], keptR[49]; int nk = 0;
        keptD[nk] = 0; keptR[nk] = Rmeas; ++nk;
        for (int i = ng - 1; i >= 0; --i) {
            bool comm = true;
            for (int k = 0; k < nk; ++k) {
                if (__builtin_parity((unsigned)(gl[i].D & keptR[k])) ||
                    __builtin_parity((unsigned)(keptD[k] & gl[i].R))) { comm = false; break; }
            }
            if (comm) gl[i].kept = false;
            else { keptD[nk] = gl[i].D; keptR[nk] = gl[i].R; ++nk; }
        }
    }
    int nkept = 0;
    for (int i = 0; i < ng; ++i) if (gl[i].kept) ++nkept;

    auto commute = [&](int i, int j) -> bool {
        return !(__builtin_parity((unsigned)(gl[i].D & gl[j].R)) ||
                 __builtin_parity((unsigned)(gl[j].D & gl[i].R)));
    };

    const int MAXP = 8;
    auto simulate = [&](uint16_t SA, uint16_t SB, int* passOf) -> int {
        for (int i = 0; i < ng; ++i) gl[i].sched = false;
        int rem = nkept, np = 0, stall = 0;
        while (rem > 0 && np < MAXP) {
            uint16_t S = (np & 1) ? SB : SA;
            int got = 0;
            for (int i = 0; i < ng; ++i) {
                if (!gl[i].kept || gl[i].sched) continue;
                if (gl[i].D & S) continue;
                bool ok = true;
                for (int j = 0; j < i; ++j) {
                    if (!gl[j].kept || gl[j].sched) continue;
                    if (!commute(i, j)) { ok = false; break; }
                }
                if (!ok) continue;
                gl[i].sched = true; --rem; ++got;
                if (passOf) passOf[i] = np;
            }
            ++np;
            if (got == 0) { if (++stall >= 2) break; } else stall = 0;
        }
        return rem == 0 ? np : 99;
    };

    // Window-pair search (LB=12: 4 excluded wires per window, consecutive runs)
    int bestNp = 99, bestA = 0, bestB = 8;
    for (int a = 0; a < 16; ++a) {
        for (int b = 0; b < 16; ++b) {
            uint16_t SA = 0, SB = 0;
            for (int k = 0; k < 4; ++k) {
                SA |= (uint16_t)(1u << ((a + k) & 15));
                SB |= (uint16_t)(1u << ((b + k) & 15));
            }
            int np = simulate(SA, SB, nullptr);
            if (np < bestNp) { bestNp = np; bestA = a; bestB = b; }
        }
    }
    uint16_t SA = 0, SB = 0;
    int exA[4], exB[4];
    for (int k = 0; k < 4; ++k) {
        exA[k] = (bestA + k) & 15; exB[k] = (bestB + k) & 15;
        SA |= (uint16_t)(1u << exA[k]); SB |= (uint16_t)(1u << exB[k]);
    }
    int passOf[48];
    for (int i = 0; i < ng; ++i) passOf[i] = -1;
    int np = simulate(SA, SB, passOf);
    if (np > MAXP) np = MAXP;
    if (np < 2) np = 2;

    // Wire -> bit position: all excluded wires at positions >= 8.
    int wireToPos[16]; bool used[16] = {};
    int pos = 15;
    for (int k = 0; k < 4; ++k) { wireToPos[exA[k]] = pos--; used[exA[k]] = true; }
    for (int k = 0; k < 4; ++k)
        if (!used[exB[k]]) { wireToPos[exB[k]] = pos--; used[exB[k]] = true; }
    for (int w = 0; w < 16; ++w) if (!used[w]) wireToPos[w] = pos--;
    int posToWire[16];
    for (int w = 0; w < 16; ++w) posToWire[wireToPos[w]] = w;

    static PassMeta pms[8];
    for (int p = 0; p < np; ++p) {
        PassMeta& M = pms[p];
        memset(&M, 0, sizeof(M));
        const int* ex = (p & 1) ? exB : exA;
        int gp[4], gw[4];
        for (int k = 0; k < 4; ++k) { gp[k] = wireToPos[ex[k]]; gw[k] = ex[k]; }
        for (int a2 = 0; a2 < 4; ++a2)
            for (int b2 = a2 + 1; b2 < 4; ++b2)
                if (gp[b2] < gp[a2]) {
                    int t = gp[a2]; gp[a2] = gp[b2]; gp[b2] = t;
                    t = gw[a2]; gw[a2] = gw[b2]; gw[b2] = t;
                }
        for (int k = 0; k < 4; ++k) { M.gap[k] = (uint8_t)gp[k]; M.nlw[k] = (uint8_t)gw[k]; }
        int packedOfWire[16];
        for (int w = 0; w < 16; ++w) packedOfWire[w] = -1;
        int t = 0;
        for (int q = 0; q < 16; ++q) {
            bool isgap = false;
            for (int k = 0; k < 4; ++k) if (q == gp[k]) isgap = true;
            if (isgap) continue;
            M.wire_of_bit[t] = (uint8_t)posToWire[q];
            packedOfWire[posToWire[q]] = t;
            ++t;
        }
        // local gate list (order preserved from simulate's schedule order)
        struct LG { uint16_t m, r; uint8_t nl, gidx; };
        LG ls[48]; int nsel = 0;
        for (int i = 0; i < ng; ++i) {
            if (!gl[i].kept || passOf[i] != p) continue;
            uint16_t m = 0, r = 0; uint8_t nl = 0;
            for (int w = 0; w < 16; ++w) {
                if ((gl[i].D >> w) & 1) m |= (uint16_t)(1u << packedOfWire[w]);
                if (((gl[i].R >> w) & 1) && packedOfWire[w] >= 0)
                    r |= (uint16_t)(1u << packedOfWire[w]);
            }
            for (int k = 0; k < 4; ++k)
                if ((gl[i].R >> gw[k]) & 1) nl |= (uint8_t)(1u << k);
            ls[nsel++] = LG{m, r, nl, gl[i].gidx};
        }
        {   // measurement masks (used only if this pass is last)
            uint16_t r = 0; uint8_t nl = 0;
            for (int w = 0; w < 16; ++w)
                if (((Rmeas >> w) & 1) && packedOfWire[w] >= 0)
                    r |= (uint16_t)(1u << packedOfWire[w]);
            for (int k = 0; k < 4; ++k)
                if ((Rmeas >> gw[k]) & 1) nl |= (uint8_t)(1u << k);
            M.meas_row = r; M.meas_nl = nl;
        }

        // ---- mega-bundling: rank-4 basis + in-span gates (4-bit mt) ----
        M.nbundles = 0;
        int rank = 0; uint16_t om[4] = {}, red[4] = {}; int pv[4] = {};
        uint8_t comb[4] = {};
        struct PG { uint16_t m, r; uint8_t nl, gidx, mt; };
        PG curg[48]; int ncur = 0; int curStart = 0;
        uint16_t lastVoff[16] = {};

        auto closeBundle = [&]() {
            if (ncur == 0) { rank = 0; return; }
            // pad basis to rank 4 with independent unit vectors
            for (int b = 11; b >= 0 && rank < 4; --b) {
                uint16_t x = (uint16_t)(1u << b); uint8_t rep = 0;
                for (int j = 0; j < rank; ++j)
                    if ((x >> pv[j]) & 1) { x ^= red[j]; rep ^= comb[j]; }
                if (!x) continue;
                om[rank] = (uint16_t)(1u << b);
                red[rank] = x; pv[rank] = 31 - __builtin_clz((unsigned)x);
                comb[rank] = (uint8_t)((1u << rank) | rep);
                ++rank;
            }
            BundleB& B = M.bd[M.nbundles];
            for (int tt = 0; tt < 16; ++tt) {
                uint16_t v = 0;
                for (int j = 0; j < 4; ++j) if ((tt >> j) & 1) v ^= om[j];
                B.voff[tt] = v; lastVoff[tt] = v;
            }
            int sp[4] = {pv[0], pv[1], pv[2], pv[3]};
            for (int a2 = 0; a2 < 4; ++a2)
                for (int b2 = a2 + 1; b2 < 4; ++b2)
                    if (sp[b2] < sp[a2]) { int tt = sp[a2]; sp[a2] = sp[b2]; sp[b2] = tt; }
            for (int j = 0; j < 4; ++j) B.piv[j] = (uint8_t)sp[j];
            B.g0 = (uint8_t)curStart; B.ng = (uint8_t)ncur;
            for (int i = 0; i < ncur; ++i) {
                int gix = curStart + i;
                M.ginfo[gix] = (uint32_t)curg[i].r
                             | ((uint32_t)curg[i].nl << 16)
                             | ((uint32_t)curg[i].gidx << 20)
                             | ((uint32_t)curg[i].mt << 28);
                uint16_t flipS = 0;
                for (int tt = 0; tt < 16; ++tt)
                    if (__builtin_parity((unsigned)(B.voff[tt] & curg[i].r)))
                        flipS |= (uint16_t)(1u << tt);
                for (int k = 0; k < 8; ++k)
                    M.maskS[gix][k] =
                        (((flipS >> (2 * k)) & 1u) ? 0x8000u : 0u) |
                        (((flipS >> (2 * k + 1)) & 1u) ? 0x80000000u : 0u);
            }
            curStart += ncur;
            ++M.nbundles;
            ncur = 0; rank = 0;
        };

        for (int i = 0; i < nsel; ++i) {
            uint16_t m = ls[i].m;
            uint16_t x = m; uint8_t rep = 0;
            for (int j = 0; j < rank; ++j)
                if ((x >> pv[j]) & 1) { x ^= red[j]; rep ^= comb[j]; }
            if (x == 0) {                         // in-span: free in-register gate
                curg[ncur++] = PG{m, ls[i].r, ls[i].nl, ls[i].gidx, rep};
            } else if (rank < 4) {                // extend basis
                om[rank] = m; red[rank] = x;
                pv[rank] = 31 - __builtin_clz((unsigned)x);
                comb[rank] = (uint8_t)((1u << rank) | rep);
                curg[ncur++] = PG{m, ls[i].r, ls[i].nl, ls[i].gidx, (uint8_t)(1u << rank)};
                ++rank;
            } else {                              // overflow: close, reseed
                closeBundle();
                om[0] = m; red[0] = m;
                pv[0] = 31 - __builtin_clz((unsigned)m);
                comb[0] = 1;
                curg[0] = PG{m, ls[i].r, ls[i].nl, ls[i].gidx, 1};
                ncur = 1; rank = 1;
            }
        }
        closeBundle();

        for (int k = 0; k < 8; ++k)
            M.measS[k] =
                (__builtin_parity((unsigned)(lastVoff[2 * k] & M.meas_row)) ? 1u : 0u) |
                (__builtin_parity((unsigned)(lastVoff[2 * k + 1] & M.meas_row)) ? 2u : 0u);
    }

    precompute_kernel<<<dim3(64), dim3(512), 0, stream>>>(X, Wt, Bs, Ug, out);
    for (int g = 0; g < ngroups; ++g) {
        const uint4* ug = Ug + (size_t)g * group * 64;
        float* og = out + (size_t)g * group;
        dim3 grid((unsigned)(group << 4));
        for (int p = 0; p < np; ++p) {
            int mode = (p == 0) ? 0 : ((p == np - 1) ? 2 : 1);
            if (mode == 0)
                pass_kernel<0><<<grid, dim3(256), 0, stream>>>(ug, state, og, pms[p]);
            else if (mode == 1)
                pass_kernel<1><<<grid, dim3(256), 0, stream>>>(ug, state, og, pms[p]);
            else
                pass_kernel<2><<<grid, dim3(256), 0, stream>>>(ug, state, og, pms[p]);
        }
    }

    (void)in_sizes; (void)n_in; (void)out_size; (void)ws_size;
}

// Round 3
// 429.065 us; speedup vs baseline: 1.1252x; 1.1252x over previous
//
#include <hip/hip_runtime.h>
#include <hip/hip_fp16.h>
#include <cstdint>
#include <cstring>

// VQR circuit simulator: 16 qubits, B=512, 4 layers.
// CNOTs are GF(2) index-relabeling bookkeeping. Fused 1q gates (SU(2)) are
// XOR-mask pair rotations. Host schedules gates into 2 window passes
// (gen+gates+store, load+gates+measure); within a pass, bundles of 4
// mask-independent gates; each thread applies a bundle on a dim-4 coset
// (16 amps). Amplitudes fp16 end-to-end. The pair update is INLINE ASM:
// 8x v_pk_fma_f16/v_pk_mul_f16 with op_sel/neg_lo/neg_hi modifiers doing
// the complex swizzles and static signs for free; runtime signs are 2
// v_xor per gate (parity) + 2 SGPR-sourced v_xor per pair (flip bit).

struct BundleMeta {
    uint16_t voff[16];   // coset offsets (local 12-bit index space)
    uint16_t row[4];     // branch parity masks (local bits), per slot
    uint16_t flip[4];    // flip[g] bit t = parity(voff[t] & row[g])
    uint8_t  piv[4];     // pivot bit positions, ASCENDING (rep expansion)
    uint8_t  gidx[4];    // gate coefficient index l*16+w; 0xFF = identity pad
    uint8_t  nl[4];      // branch parity masks over the 4 chunk bits
};

struct PassMeta {
    int       nbundles;
    BundleMeta bd[24];
    uint8_t   gap[4];          // non-local bit positions, ASCENDING (all >=8)
    uint8_t   nlw[4];          // chunk bit k -> wire
    uint8_t   wire_of_bit[12]; // packed LDS bit -> wire (product-state init)
    uint16_t  meas_row;        // measurement parity mask (local bits)
    uint8_t   meas_nl;         // measurement parity mask (chunk bits)
};

typedef _Float16 h2 __attribute__((ext_vector_type(2)));

__device__ __forceinline__ float2 cmul2(float2 a, float2 b) {
    return make_float2(a.x * b.x - a.y * b.y, a.x * b.y + a.y * b.x);
}
__device__ __forceinline__ h2 pkfma(h2 a, h2 b, h2 c) {
    return __builtin_bit_cast(h2, __hfma2(__builtin_bit_cast(__half2, a),
                                          __builtin_bit_cast(__half2, b),
                                          __builtin_bit_cast(__half2, c)));
}
__device__ __forceinline__ h2 h2x(h2 a, unsigned m) {
    return __builtin_bit_cast(h2, __builtin_bit_cast(unsigned, a) ^ m);
}
__device__ __forceinline__ h2 bch2(unsigned u) { return __builtin_bit_cast(h2, u); }
__device__ __forceinline__ unsigned pkh2(float lo, float hi) {
    h2 v; v.x = (_Float16)lo; v.y = (_Float16)hi;
    return __builtin_bit_cast(unsigned, v);
}

// Pair rotation, exact VOP3P codegen. Amps packed (re,im) = (lo,hi).
// AR=[ar,ar] AIt=[tai,tai] BRt=[tbr,tbr] BI=[bi,bi]  (tai/tbr sign-applied)
//   np = (ar*pr - tai*pi + tbr*qr - bi*qi , ar*pi + tai*pr + tbr*qi + bi*qr)
//   nq = (-tbr*pr - bi*pi + ar*qr + tai*qi , -tbr*pi + bi*pr + ar*qi - tai*qr)
__device__ __forceinline__ void pair_rot(unsigned& np, unsigned& nq,
    unsigned p, unsigned q, unsigned AR, unsigned AIt, unsigned BRt, unsigned BI)
{
    unsigned a, b;
    asm("v_pk_mul_f16 %0, %1, %3\n\t"
        "v_pk_fma_f16 %0, %2, %3, %0 op_sel:[0,1,0] op_sel_hi:[1,0,1] neg_lo:[1,0,0]\n\t"
        "v_pk_fma_f16 %0, %4, %5, %0\n\t"
        "v_pk_fma_f16 %0, %6, %5, %0 op_sel:[0,1,0] op_sel_hi:[1,0,1] neg_lo:[1,0,0]"
        : "=&v"(a)
        : "v"(AR), "v"(AIt), "v"(p), "v"(BRt), "v"(q), "v"(BI));
    asm("v_pk_mul_f16 %0, %1, %5\n\t"
        "v_pk_fma_f16 %0, %2, %5, %0 op_sel:[0,1,0] op_sel_hi:[1,0,1] neg_hi:[1,0,0]\n\t"
        "v_pk_fma_f16 %0, %4, %3, %0 neg_lo:[1,0,0] neg_hi:[1,0,0]\n\t"
        "v_pk_fma_f16 %0, %6, %3, %0 op_sel:[0,1,0] op_sel_hi:[1,0,1] neg_lo:[1,0,0]"
        : "=&v"(b)
        : "v"(AR), "v"(AIt), "v"(p), "v"(BRt), "v"(q), "v"(BI));
    np = a; nq = b;
}

// Fused U = Rz(t2)Ry(t1)Rz(t0)Rx(enc), enc = 2*atan(x).
// Emit packed-h2 quad, plain signs: [ar,ar] [ai,ai] [br,br] [bi,bi].
__global__ __launch_bounds__(512)
void precompute_kernel(const float* __restrict__ X, const float* __restrict__ Wt,
                       const float* __restrict__ Bs, uint4* __restrict__ Ug,
                       float* __restrict__ out)
{
    int id = blockIdx.x * 512 + threadIdx.x;
    if (id >= 512 * 64) return;
    int b = id >> 6, lw = id & 63, l = lw >> 4, w = lw & 15;
    float x  = X[b * 16 + w];
    float ce = 1.0f / sqrtf(1.0f + x * x);
    float se = x * ce;
    float t0 = 0.5f * Wt[(l * 16 + w) * 3 + 0];
    float t1 = 0.5f * Wt[(l * 16 + w) * 3 + 1];
    float t2 = 0.5f * Wt[(l * 16 + w) * 3 + 2];
    float c1 = cosf(t1), s1 = sinf(t1);
    float ca = cosf(t0 + t2), sa = sinf(t0 + t2);
    float cb = cosf(t2 - t0), sb = sinf(t2 - t0);
    float2 W00 = make_float2( c1 * ca, -c1 * sa);
    float2 W01 = make_float2(-s1 * cb,  s1 * sb);
    float2 a  = make_float2(W00.x * ce + W01.y * se, W00.y * ce - W01.x * se);
    float2 bb = make_float2(W00.y * se + W01.x * ce, -W00.x * se + W01.y * ce);
    uint4 o;
    o.x = pkh2(a.x,  a.x);    // AR
    o.y = pkh2(a.y,  a.y);    // AI
    o.z = pkh2(bb.x, bb.x);   // BR
    o.w = pkh2(bb.y, bb.y);   // BI
    Ug[id] = o;
    if (lw == 0) out[b] = Bs[0];
}

// MODE 0: generate product state + gates + store (fp16)
// MODE 1: load + gates + store (in-place, fp16)
// MODE 2: load + gates + measurement reduce (no store)
template <int MODE>
__global__ __launch_bounds__(256, 6)
void pass_kernel(const uint4* __restrict__ Ug, unsigned* __restrict__ state,
                 float* __restrict__ out, PassMeta meta)
{
    __shared__ __align__(16) unsigned amp[4096];   // 16 KiB (one half2 per amp)
    __shared__ uint4 coef[64];                     // packed-h2 gate quads (1 KiB)
    const int tid = threadIdx.x;
    const int bb  = blockIdx.x >> 4;
    const unsigned c = blockIdx.x & 15u;
    const size_t base = (size_t)bb << 16;
    if (tid < 64) coef[tid] = Ug[(size_t)bb * 64 + tid];

    auto expand = [&](unsigned x) -> unsigned {   // gaps ascending, all >= 8
        #pragma unroll
        for (int k = 0; k < 4; ++k) {
            unsigned g = meta.gap[k];
            x = ((x >> g) << (g + 1)) | (x & ((1u << g) - 1u)) | (((c >> k) & 1u) << g);
        }
        return x;
    };

    if constexpr (MODE == 0) {
        __syncthreads();   // coef ready
        if (tid == 0) {
            float2 kv = make_float2(1.f, 0.f);
            for (int t = 0; t < 4; ++t) {
                uint4 u = coef[meta.nlw[t]];
                float ar = (float)bch2(u.x).x, ai = (float)bch2(u.y).x;
                float br = (float)bch2(u.z).x, bi = (float)bch2(u.w).x;
                float2 col = ((c >> t) & 1u) ? make_float2(-br, bi)
                                             : make_float2(ar, ai);
                kv = cmul2(kv, col);
            }
            amp[0] = pkh2(kv.x, kv.y);
        }
        __syncthreads();
        for (int s = 0; s < 12; ++s) {
            const int n = 1 << s;
            uint4 cf = coef[meta.wire_of_bit[s]];
            const h2 AR2  = bch2(cf.x);
            const h2 AIpm = h2x(bch2(cf.y), 0x00008000u);  // [-ai, ai]
            const h2 BRn  = h2x(bch2(cf.z), 0x80008000u);  // [-br,-br]
            const h2 BIpm = h2x(bch2(cf.w), 0x00008000u);  // [-bi, bi]
            for (int i = tid; i < n; i += 256) {
                h2 a = bch2(amp[i]);
                h2 sw = a.yx;
                amp[i + n] = __builtin_bit_cast(unsigned, pkfma(BRn, a, BIpm * sw));
                amp[i]     = __builtin_bit_cast(unsigned, pkfma(AR2, a, AIpm * sw));
            }
            __syncthreads();
        }
    } else {
        #pragma unroll
        for (int it = 0; it < 4; ++it) {
            unsigned u = (unsigned)(tid + it * 256) * 4u;
            unsigned a = expand(u);
            uint4 v = *reinterpret_cast<const uint4*>(state + base + a);
            *reinterpret_cast<uint4*>(&amp[u]) = v;   // 4 amps = 16 B, b128
        }
        __syncthreads();   // also covers coef staging
    }

    for (int ci = 0; ci < meta.nbundles; ++ci) {
        const BundleMeta& B = meta.bd[ci];
        unsigned r = (unsigned)tid;
        #pragma unroll
        for (int k = 0; k < 4; ++k) {
            unsigned p = B.piv[k];
            r = ((r >> p) << (p + 1)) | (r & ((1u << p) - 1u));
        }
        const unsigned rb = r << 2;   // byte offset; xor with voff<<2 (scalar)
        unsigned a_[16];
        #pragma unroll
        for (int t = 0; t < 16; ++t)
            a_[t] = *(const unsigned*)((const char*)amp + (rb ^ ((unsigned)B.voff[t] << 2)));
        #pragma unroll
        for (int g = 0; g < 4; ++g) {
            if (B.gidx[g] == 0xFF) continue;       // identity pad (uniform skip)
            const uint4 cf = coef[B.gidx[g]];
            const unsigned par = ((unsigned)__popc(r & (unsigned)B.row[g]) +
                                  (unsigned)__popc((unsigned)B.nl[g] & c)) & 1u;
            const unsigned gm = par ? 0x80008000u : 0u;
            const unsigned AR  = cf.x;
            const unsigned AIg = cf.y ^ gm;
            const unsigned BRg = cf.z ^ gm;
            const unsigned BI  = cf.w;
            const unsigned fl  = B.flip[g];
            #pragma unroll
            for (int t = 0; t < 16; ++t) {
                if (t & (1 << g)) continue;
                const int t2 = t | (1 << g);
                const unsigned fbm = ((fl >> t) & 1u) * 0x80008000u;  // uniform (SGPR)
                const unsigned AIt = AIg ^ fbm;
                const unsigned BRt = BRg ^ fbm;
                unsigned np, nq;
                pair_rot(np, nq, a_[t], a_[t2], AR, AIt, BRt, BI);
                a_[t] = np; a_[t2] = nq;
            }
        }
        if (MODE == 2 && ci == meta.nbundles - 1) {
            // measure directly from registers (skip final LDS round-trip)
            float acc = 0.f;
            const unsigned mcp = (unsigned)(__popc((unsigned)meta.meas_nl & c) & 1);
            #pragma unroll
            for (int t = 0; t < 16; ++t) {
                h2 a = bch2(a_[t]);
                float vr = (float)a.x, vi = (float)a.y;
                float pr = __builtin_fmaf(vr, vr, vi * vi);
                unsigned sg2 = ((unsigned)__popc((r ^ (unsigned)B.voff[t]) &
                               (unsigned)meta.meas_row) & 1u) ^ mcp;
                acc += sg2 ? -pr : pr;
            }
            for (int off = 32; off > 0; off >>= 1) acc += __shfl_down(acc, off, 64);
            if ((tid & 63) == 0) atomicAdd(&out[bb], acc);
            return;
        }
        #pragma unroll
        for (int t = 0; t < 16; ++t)
            *(unsigned*)((char*)amp + (rb ^ ((unsigned)B.voff[t] << 2))) = a_[t];
        __syncthreads();
    }

    if constexpr (MODE == 2) {
        // fallback (only if nbundles==0): measure from LDS
        float acc = 0.f;
        const unsigned mcp = (unsigned)(__popc((unsigned)meta.meas_nl & c) & 1);
        for (int k = 0; k < 16; ++k) {
            unsigned u = (unsigned)(tid + k * 256);
            h2 a = bch2(amp[u]);
            float vr = (float)a.x, vi = (float)a.y;
            float pr = __builtin_fmaf(vr, vr, vi * vi);
            acc += (((unsigned)__popc(u & (unsigned)meta.meas_row) & 1u) ^ mcp)
                 ? -pr : pr;
        }
        for (int off = 32; off > 0; off >>= 1) acc += __shfl_down(acc, off, 64);
        if ((tid & 63) == 0) atomicAdd(&out[bb], acc);
    } else {
        #pragma unroll
        for (int it = 0; it < 4; ++it) {
            unsigned u = (unsigned)(tid + it * 256) * 4u;
            unsigned ad = expand(u);
            uint4 v = *reinterpret_cast<const uint4*>(&amp[u]);
            *reinterpret_cast<uint4*>(state + base + ad) = v;
        }
    }
}

extern "C" void kernel_launch(void* const* d_in, const int* in_sizes, int n_in,
                              void* d_out, int out_size, void* d_ws, size_t ws_size,
                              hipStream_t stream)
{
    const float* X  = (const float*)d_in[0];
    const float* Wt = (const float*)d_in[1];
    const float* Bs = (const float*)d_in[2];
    float* out = (float*)d_out;

    const size_t UG_BYTES = (size_t)512 * 64 * sizeof(uint4);  // 512 KiB
    uint4*    Ug    = (uint4*)d_ws;
    unsigned* state = (unsigned*)((char*)d_ws + UG_BYTES);
    size_t avail = ws_size > UG_BYTES ? ws_size - UG_BYTES : 0;
    int group = 1;   // fp16 state: 256 KiB per batch element
    while (group < 512 && (size_t)(group * 2) * 262144ull <= avail)
        group <<= 1;
    const int ngroups = 512 / group;

    // ---- GF(2) bookkeeping (sequential CNOT ring, matches reference) ----
    uint16_t D[16], R[16];
    for (int w = 0; w < 16; ++w) { D[w] = R[w] = (uint16_t)(1u << w); }
    struct G { uint16_t D, R; uint8_t gidx; bool kept; bool sched; };
    G gl[48]; int ng = 0;
    for (int l = 1; l <= 3; ++l) {
        for (int w = 0; w < 16; ++w) { int t = (w + 1) & 15; D[w] ^= D[t]; R[t] ^= R[w]; }
        for (int w = 0; w < 16; ++w)
            gl[ng++] = G{D[w], R[w], (uint8_t)(l * 16 + w), true, false};
    }
    for (int w = 0; w < 16; ++w) { int t = (w + 1) & 15; D[w] ^= D[t]; R[t] ^= R[w]; }
    const uint16_t Rmeas = R[0];

    // Backward prune
    {
        uint16_t keptD[49], keptR[49]; int nk = 0;
        keptD[nk] = 0; keptR[nk] = Rmeas; ++nk;
        for (int i = ng - 1; i >= 0; --i) {
            bool comm = true;
            for (int k = 0; k < nk; ++k) {
                if (__builtin_parity((unsigned)(gl[i].D & keptR[k])) ||
                    __builtin_parity((unsigned)(keptD[k] & gl[i].R))) { comm = false; break; }
            }
            if (comm) gl[i].kept = false;
            else { keptD[nk] = gl[i].D; keptR[nk] = gl[i].R; ++nk; }
        }
    }
    int nkept = 0;
    for (int i = 0; i < ng; ++i) if (gl[i].kept) ++nkept;

    auto commute = [&](int i, int j) -> bool {
        return !(__builtin_parity((unsigned)(gl[i].D & gl[j].R)) ||
                 __builtin_parity((unsigned)(gl[j].D & gl[i].R)));
    };

    const int MAXP = 8;
    auto simulate = [&](uint16_t SA, uint16_t SB, int* passOf) -> int {
        for (int i = 0; i < ng; ++i) gl[i].sched = false;
        int rem = nkept, np = 0, stall = 0;
        while (rem > 0 && np < MAXP) {
            uint16_t S = (np & 1) ? SB : SA;
            int got = 0;
            for (int i = 0; i < ng; ++i) {
                if (!gl[i].kept || gl[i].sched) continue;
                if (gl[i].D & S) continue;
                bool ok = true;
                for (int j = 0; j < i; ++j) {
                    if (!gl[j].kept || gl[j].sched) continue;
                    if (!commute(i, j)) { ok = false; break; }
                }
                if (!ok) continue;
                gl[i].sched = true; --rem; ++got;
                if (passOf) passOf[i] = np;
            }
            ++np;
            if (got == 0) { if (++stall >= 2) break; } else stall = 0;
        }
        return rem == 0 ? np : 99;
    };

    // Window-pair search (LB=12: 4 excluded wires per window, consecutive runs)
    int bestNp = 99, bestA = 0, bestB = 8;
    for (int a = 0; a < 16; ++a) {
        for (int b = 0; b < 16; ++b) {
            uint16_t SA = 0, SB = 0;
            for (int k = 0; k < 4; ++k) {
                SA |= (uint16_t)(1u << ((a + k) & 15));
                SB |= (uint16_t)(1u << ((b + k) & 15));
            }
            int np = simulate(SA, SB, nullptr);
            if (np < bestNp) { bestNp = np; bestA = a; bestB = b; }
        }
    }
    uint16_t SA = 0, SB = 0;
    int exA[4], exB[4];
    for (int k = 0; k < 4; ++k) {
        exA[k] = (bestA + k) & 15; exB[k] = (bestB + k) & 15;
        SA |= (uint16_t)(1u << exA[k]); SB |= (uint16_t)(1u << exB[k]);
    }
    int passOf[48];
    for (int i = 0; i < ng; ++i) passOf[i] = -1;
    int np = simulate(SA, SB, passOf);
    if (np > MAXP) np = MAXP;
    if (np < 2) np = 2;

    // Wire -> bit position: all excluded wires at positions >= 8.
    int wireToPos[16]; bool used[16] = {};
    int pos = 15;
    for (int k = 0; k < 4; ++k) { wireToPos[exA[k]] = pos--; used[exA[k]] = true; }
    for (int k = 0; k < 4; ++k)
        if (!used[exB[k]]) { wireToPos[exB[k]] = pos--; used[exB[k]] = true; }
    for (int w = 0; w < 16; ++w) if (!used[w]) wireToPos[w] = pos--;
    int posToWire[16];
    for (int w = 0; w < 16; ++w) posToWire[wireToPos[w]] = w;

    static PassMeta pms[8];
    for (int p = 0; p < np; ++p) {
        PassMeta& M = pms[p];
        memset(&M, 0, sizeof(M));
        const int* ex = (p & 1) ? exB : exA;
        int gp[4], gw[4];
        for (int k = 0; k < 4; ++k) { gp[k] = wireToPos[ex[k]]; gw[k] = ex[k]; }
        for (int a2 = 0; a2 < 4; ++a2)
            for (int b2 = a2 + 1; b2 < 4; ++b2)
                if (gp[b2] < gp[a2]) {
                    int t = gp[a2]; gp[a2] = gp[b2]; gp[b2] = t;
                    t = gw[a2]; gw[a2] = gw[b2]; gw[b2] = t;
                }
        for (int k = 0; k < 4; ++k) { M.gap[k] = (uint8_t)gp[k]; M.nlw[k] = (uint8_t)gw[k]; }
        int packedOfWire[16];
        for (int w = 0; w < 16; ++w) packedOfWire[w] = -1;
        int t = 0;
        for (int q = 0; q < 16; ++q) {
            bool isgap = false;
            for (int k = 0; k < 4; ++k) if (q == gp[k]) isgap = true;
            if (isgap) continue;
            M.wire_of_bit[t] = (uint8_t)posToWire[q];
            packedOfWire[posToWire[q]] = t;
            ++t;
        }
        // local gate list (order preserved from simulate's schedule order)
        struct LG { uint16_t m, r; uint8_t nl, gidx; };
        LG ls[48]; int nsel = 0;
        for (int i = 0; i < ng; ++i) {
            if (!gl[i].kept || passOf[i] != p) continue;
            uint16_t m = 0, r = 0; uint8_t nl = 0;
            for (int w = 0; w < 16; ++w) {
                if ((gl[i].D >> w) & 1) m |= (uint16_t)(1u << packedOfWire[w]);
                if (((gl[i].R >> w) & 1) && packedOfWire[w] >= 0)
                    r |= (uint16_t)(1u << packedOfWire[w]);
            }
            for (int k = 0; k < 4; ++k)
                if ((gl[i].R >> gw[k]) & 1) nl |= (uint8_t)(1u << k);
            ls[nsel++] = LG{m, r, nl, gl[i].gidx};
        }
        // bundle into groups of <=4 with independent masks (consecutive)
        M.nbundles = 0;
        int s = 0;
        while (s < nsel && M.nbundles < 24) {
            BundleMeta& B = M.bd[M.nbundles++];
            for (int j = 0; j < 4; ++j) {
                B.gidx[j] = 0xFF; B.row[j] = 0; B.flip[j] = 0; B.nl[j] = 0;
            }
            uint16_t red[4], om[4]; int pv[4]; int nsl = 0;
            while (nsl < 4 && s < nsel) {
                uint16_t r0 = ls[s].m;
                for (int j = 0; j < nsl; ++j)
                    if ((r0 >> pv[j]) & 1) r0 ^= red[j];
                if (!r0) break;    // dependent -> close bundle
                pv[nsl] = 31 - __builtin_clz((unsigned)r0);
                red[nsl] = r0; om[nsl] = ls[s].m;
                B.gidx[nsl] = ls[s].gidx; B.row[nsl] = ls[s].r; B.nl[nsl] = ls[s].nl;
                ++nsl; ++s;
            }
            for (int b = 11; b >= 0 && nsl < 4; --b) {   // pad basis
                uint16_t r0 = (uint16_t)(1u << b);
                for (int j = 0; j < nsl; ++j)
                    if ((r0 >> pv[j]) & 1) r0 ^= red[j];
                if (!r0) continue;
                pv[nsl] = 31 - __builtin_clz((unsigned)r0);
                red[nsl] = r0; om[nsl] = (uint16_t)(1u << b);
                ++nsl;
            }
            for (int tt = 0; tt < 16; ++tt) {
                uint16_t v = 0;
                for (int j = 0; j < 4; ++j) if ((tt >> j) & 1) v ^= om[j];
                B.voff[tt] = v;
            }
            for (int j = 0; j < 4; ++j) {
                if (B.gidx[j] == 0xFF) continue;
                uint16_t f = 0;
                for (int tt = 0; tt < 16; ++tt)
                    if (__builtin_parity((unsigned)(B.voff[tt] & B.row[j])))
                        f |= (uint16_t)(1u << tt);
                B.flip[j] = f;
            }
            for (int a2 = 0; a2 < 4; ++a2)
                for (int b2 = a2 + 1; b2 < 4; ++b2)
                    if (pv[b2] < pv[a2]) { int tt = pv[a2]; pv[a2] = pv[b2]; pv[b2] = tt; }
            for (int j = 0; j < 4; ++j) B.piv[j] = (uint8_t)pv[j];
        }
        {   // measurement masks (used only if this pass is last)
            uint16_t r = 0; uint8_t nl = 0;
            for (int w = 0; w < 16; ++w)
                if (((Rmeas >> w) & 1) && packedOfWire[w] >= 0)
                    r |= (uint16_t)(1u << packedOfWire[w]);
            for (int k = 0; k < 4; ++k)
                if ((Rmeas >> gw[k]) & 1) nl |= (uint8_t)(1u << k);
            M.meas_row = r; M.meas_nl = nl;
        }
    }

    precompute_kernel<<<dim3(64), dim3(512), 0, stream>>>(X, Wt, Bs, Ug, out);
    for (int g = 0; g < ngroups; ++g) {
        const uint4* ug = Ug + (size_t)g * group * 64;
        float* og = out + (size_t)g * group;
        dim3 grid((unsigned)(group << 4));
        for (int p = 0; p < np; ++p) {
            int mode = (p == 0) ? 0 : ((p == np - 1) ? 2 : 1);
            if (mode == 0)
                pass_kernel<0><<<grid, dim3(256), 0, stream>>>(ug, state, og, pms[p]);
            else if (mode == 1)
                pass_kernel<1><<<grid, dim3(256), 0, stream>>>(ug, state, og, pms[p]);
            else
                pass_kernel<2><<<grid, dim3(256), 0, stream>>>(ug, state, og, pms[p]);
        }
    }

    (void)in_sizes; (void)n_in; (void)out_size; (void)ws_size;
}

// Round 4
// 330.070 us; speedup vs baseline: 1.4627x; 1.2999x over previous
//
#include <hip/hip_runtime.h>
#include <hip/hip_fp16.h>
#include <cstdint>
#include <cstring>

// VQR circuit simulator: 16 qubits, B=512, 4 layers.
// CNOTs are GF(2) index-relabeling bookkeeping. Fused 1q gates (SU(2)) are
// XOR-mask pair rotations. The ENTIRE gate schedule (window passes, bundles,
// coset offsets, pivots, sign masks) is data-independent -> computed at
// COMPILE TIME via constexpr and baked into the kernel as immediates:
// no kernarg meta, no SGPR pressure, per-pair flip signs are compile-time
// register selection, LDS address xors use literals. Pair update is inline
// VOP3P asm (8 packed ops/pair). Amplitudes fp16 end-to-end.

struct BundleMeta {
    uint16_t voff[16];   // coset offsets (local 12-bit index space)
    uint16_t row[4];     // branch parity masks (local bits), per slot
    uint16_t flip[4];    // flip[g] bit t = parity(voff[t] & row[g])
    uint8_t  piv[4];     // pivot bit positions, ASCENDING (rep expansion)
    uint8_t  gidx[4];    // gate coefficient index l*16+w; 0xFF = identity pad
    uint8_t  nl[4];      // branch parity masks over the 4 chunk bits
};

struct PassMeta {
    int       nbundles;
    BundleMeta bd[24];
    uint8_t   gap[4];          // non-local bit positions, ASCENDING (all >=8)
    uint8_t   nlw[4];          // chunk bit k -> wire
    uint8_t   wire_of_bit[12]; // packed LDS bit -> wire (product-state init)
    uint16_t  meas_row;        // measurement parity mask (local bits)
    uint8_t   meas_nl;         // measurement parity mask (chunk bits)
};

struct Sched { int np; PassMeta pms[8]; };

// ---------------- compile-time schedule builder ----------------
constexpr Sched build_sched() {
    Sched S{};
    const int MAXP = 8;
    uint16_t D[16]{}, R[16]{};
    for (int w = 0; w < 16; ++w) { D[w] = R[w] = (uint16_t)(1u << w); }
    uint16_t gD[48]{}, gR[48]{}; uint8_t ggi[48]{}; bool gk[48]{};
    int ng = 0;
    for (int l = 1; l <= 3; ++l) {
        for (int w = 0; w < 16; ++w) { int t = (w + 1) & 15; D[w] ^= D[t]; R[t] ^= R[w]; }
        for (int w = 0; w < 16; ++w) {
            gD[ng] = D[w]; gR[ng] = R[w]; ggi[ng] = (uint8_t)(l * 16 + w);
            gk[ng] = true; ++ng;
        }
    }
    for (int w = 0; w < 16; ++w) { int t = (w + 1) & 15; D[w] ^= D[t]; R[t] ^= R[w]; }
    const uint16_t Rmeas = R[0];
    {   // backward prune
        uint16_t keptD[49]{}, keptR[49]{}; int nk = 0;
        keptD[nk] = 0; keptR[nk] = Rmeas; ++nk;
        for (int i = ng - 1; i >= 0; --i) {
            bool comm = true;
            for (int k = 0; k < nk; ++k) {
                if (__builtin_parity((unsigned)(gD[i] & keptR[k])) ||
                    __builtin_parity((unsigned)(keptD[k] & gR[i]))) { comm = false; break; }
            }
            if (comm) gk[i] = false;
            else { keptD[nk] = gD[i]; keptR[nk] = gR[i]; ++nk; }
        }
    }
    int nkept = 0; unsigned long long keptM = 0;
    for (int i = 0; i < ng; ++i) if (gk[i]) { ++nkept; keptM |= 1ull << i; }
    unsigned long long cm[48]{};
    for (int i = 0; i < ng; ++i)
        for (int j = 0; j < ng; ++j)
            if (!(__builtin_parity((unsigned)(gD[i] & gR[j])) ||
                  __builtin_parity((unsigned)(gD[j] & gR[i]))))
                cm[i] |= 1ull << j;
    int passOf[48]{};
    for (int i = 0; i < ng; ++i) passOf[i] = -1;
    auto bitsim = [&](uint16_t SA_, uint16_t SB_, int maxnp, int* po) -> int {
        unsigned long long sc = 0; int rem = nkept, npp = 0, stall = 0;
        while (rem > 0 && npp < MAXP) {
            uint16_t Sm = (npp & 1) ? SB_ : SA_;
            int got = 0;
            for (int i = 0; i < ng; ++i) {
                unsigned long long bi = 1ull << i;
                if (!(keptM & bi) || (sc & bi)) continue;
                if (gD[i] & Sm) continue;
                unsigned long long prior = keptM & ~sc & (bi - 1ull);
                if (prior & ~cm[i]) continue;
                sc |= bi; --rem; ++got;
                if (po) po[i] = npp;
            }
            ++npp;
            if (!got) { if (++stall >= 2) break; } else stall = 0;
            if (rem > 0 && npp >= maxnp) return 99;
        }
        return rem == 0 ? npp : 99;
    };
    int bestA = -1, bestB = 0;
    for (int target = 2; target <= MAXP && bestA < 0; ++target)
        for (int a = 0; a < 16 && bestA < 0; ++a)
            for (int b = 0; b < 16; ++b) {
                uint16_t SA_ = 0, SB_ = 0;
                for (int k = 0; k < 4; ++k) {
                    SA_ |= (uint16_t)(1u << ((a + k) & 15));
                    SB_ |= (uint16_t)(1u << ((b + k) & 15));
                }
                int rv = bitsim(SA_, SB_, target, nullptr);
                if (rv <= target) { bestA = a; bestB = b; break; }
            }
    if (bestA < 0) { bestA = 0; bestB = 8; }
    uint16_t SA = 0, SB = 0;
    int exA[4]{}, exB[4]{};
    for (int k = 0; k < 4; ++k) {
        exA[k] = (bestA + k) & 15; exB[k] = (bestB + k) & 15;
        SA |= (uint16_t)(1u << exA[k]); SB |= (uint16_t)(1u << exB[k]);
    }
    int np = bitsim(SA, SB, MAXP, passOf);
    if (np > MAXP) np = MAXP;
    if (np < 2) np = 2;
    int wireToPos[16]{}; bool used[16]{};
    int pos = 15;
    for (int k = 0; k < 4; ++k) { wireToPos[exA[k]] = pos--; used[exA[k]] = true; }
    for (int k = 0; k < 4; ++k)
        if (!used[exB[k]]) { wireToPos[exB[k]] = pos--; used[exB[k]] = true; }
    for (int w = 0; w < 16; ++w) if (!used[w]) wireToPos[w] = pos--;
    int posToWire[16]{};
    for (int w = 0; w < 16; ++w) posToWire[wireToPos[w]] = w;
    for (int p = 0; p < np; ++p) {
        PassMeta& M = S.pms[p];
        const int* ex = (p & 1) ? exB : exA;
        int gp[4]{}, gw[4]{};
        for (int k = 0; k < 4; ++k) { gp[k] = wireToPos[ex[k]]; gw[k] = ex[k]; }
        for (int a2 = 0; a2 < 4; ++a2)
            for (int b2 = a2 + 1; b2 < 4; ++b2)
                if (gp[b2] < gp[a2]) {
                    int t = gp[a2]; gp[a2] = gp[b2]; gp[b2] = t;
                    t = gw[a2]; gw[a2] = gw[b2]; gw[b2] = t;
                }
        for (int k = 0; k < 4; ++k) { M.gap[k] = (uint8_t)gp[k]; M.nlw[k] = (uint8_t)gw[k]; }
        int packedOfWire[16]{};
        for (int w = 0; w < 16; ++w) packedOfWire[w] = -1;
        int t = 0;
        for (int q = 0; q < 16; ++q) {
            bool isgap = false;
            for (int k = 0; k < 4; ++k) if (q == gp[k]) isgap = true;
            if (isgap) continue;
            M.wire_of_bit[t] = (uint8_t)posToWire[q];
            packedOfWire[posToWire[q]] = t;
            ++t;
        }
        uint16_t lm[48]{}, lr[48]{}; uint8_t lnl[48]{}, lgx[48]{}; int nsel = 0;
        for (int i = 0; i < ng; ++i) {
            if (!gk[i] || passOf[i] != p) continue;
            uint16_t m = 0, r = 0; uint8_t nl = 0;
            for (int w = 0; w < 16; ++w) {
                if ((gD[i] >> w) & 1) m |= (uint16_t)(1u << packedOfWire[w]);
                if (((gR[i] >> w) & 1) && packedOfWire[w] >= 0)
                    r |= (uint16_t)(1u << packedOfWire[w]);
            }
            for (int k = 0; k < 4; ++k)
                if ((gR[i] >> gw[k]) & 1) nl |= (uint8_t)(1u << k);
            lm[nsel] = m; lr[nsel] = r; lnl[nsel] = nl; lgx[nsel] = ggi[i]; ++nsel;
        }
        M.nbundles = 0;
        int s = 0;
        while (s < nsel && M.nbundles < 24) {
            BundleMeta& B = M.bd[M.nbundles]; ++M.nbundles;
            for (int j = 0; j < 4; ++j) {
                B.gidx[j] = 0xFF; B.row[j] = 0; B.flip[j] = 0; B.nl[j] = 0;
            }
            uint16_t red[4]{}, om[4]{}; int pv[4]{}; int nsl = 0;
            while (nsl < 4 && s < nsel) {
                uint16_t r0 = lm[s];
                for (int j = 0; j < nsl; ++j)
                    if ((r0 >> pv[j]) & 1) r0 ^= red[j];
                if (!r0) break;
                pv[nsl] = 31 - __builtin_clz((unsigned)r0);
                red[nsl] = r0; om[nsl] = lm[s];
                B.gidx[nsl] = lgx[s]; B.row[nsl] = lr[s]; B.nl[nsl] = lnl[s];
                ++nsl; ++s;
            }
            for (int b = 11; b >= 0 && nsl < 4; --b) {
                uint16_t r0 = (uint16_t)(1u << b);
                for (int j = 0; j < nsl; ++j)
                    if ((r0 >> pv[j]) & 1) r0 ^= red[j];
                if (!r0) continue;
                pv[nsl] = 31 - __builtin_clz((unsigned)r0);
                red[nsl] = r0; om[nsl] = (uint16_t)(1u << b);
                ++nsl;
            }
            for (int tt = 0; tt < 16; ++tt) {
                uint16_t v = 0;
                for (int j = 0; j < 4; ++j) if ((tt >> j) & 1) v ^= om[j];
                B.voff[tt] = v;
            }
            for (int j = 0; j < 4; ++j) {
                if (B.gidx[j] == 0xFF) continue;
                uint16_t f = 0;
                for (int tt = 0; tt < 16; ++tt)
                    if (__builtin_parity((unsigned)(B.voff[tt] & B.row[j])))
                        f |= (uint16_t)(1u << tt);
                B.flip[j] = f;
            }
            for (int a2 = 0; a2 < 4; ++a2)
                for (int b2 = a2 + 1; b2 < 4; ++b2)
                    if (pv[b2] < pv[a2]) { int tt = pv[a2]; pv[a2] = pv[b2]; pv[b2] = tt; }
            for (int j = 0; j < 4; ++j) B.piv[j] = (uint8_t)pv[j];
        }
        {
            uint16_t r = 0; uint8_t nl = 0;
            for (int w = 0; w < 16; ++w)
                if (((Rmeas >> w) & 1) && packedOfWire[w] >= 0)
                    r |= (uint16_t)(1u << packedOfWire[w]);
            for (int k = 0; k < 4; ++k)
                if ((Rmeas >> gw[k]) & 1) nl |= (uint8_t)(1u << k);
            M.meas_row = r; M.meas_nl = nl;
        }
    }
    S.np = np;
    return S;
}

constexpr Sched SCHED = build_sched();

// ---------------- device ----------------
typedef _Float16 h2 __attribute__((ext_vector_type(2)));

__device__ __forceinline__ float2 cmul2(float2 a, float2 b) {
    return make_float2(a.x * b.x - a.y * b.y, a.x * b.y + a.y * b.x);
}
__device__ __forceinline__ h2 pkfma(h2 a, h2 b, h2 c) {
    return __builtin_bit_cast(h2, __hfma2(__builtin_bit_cast(__half2, a),
                                          __builtin_bit_cast(__half2, b),
                                          __builtin_bit_cast(__half2, c)));
}
__device__ __forceinline__ h2 h2x(h2 a, unsigned m) {
    return __builtin_bit_cast(h2, __builtin_bit_cast(unsigned, a) ^ m);
}
__device__ __forceinline__ h2 bch2(unsigned u) { return __builtin_bit_cast(h2, u); }
__device__ __forceinline__ float xorf(float a, unsigned s) {
    return __uint_as_float(__float_as_uint(a) ^ s);
}
__device__ __forceinline__ unsigned pkh2(float lo, float hi) {
    h2 v; v.x = (_Float16)lo; v.y = (_Float16)hi;
    return __builtin_bit_cast(unsigned, v);
}

// Pair rotation, exact VOP3P codegen (verified R2). Amps packed (re,im)=(lo,hi).
__device__ __forceinline__ void pair_rot(unsigned& np_, unsigned& nq_,
    unsigned p, unsigned q, unsigned AR, unsigned AIt, unsigned BRt, unsigned BI)
{
    unsigned a, b;
    asm("v_pk_mul_f16 %0, %1, %3\n\t"
        "v_pk_fma_f16 %0, %2, %3, %0 op_sel:[0,1,0] op_sel_hi:[1,0,1] neg_lo:[1,0,0]\n\t"
        "v_pk_fma_f16 %0, %4, %5, %0\n\t"
        "v_pk_fma_f16 %0, %6, %5, %0 op_sel:[0,1,0] op_sel_hi:[1,0,1] neg_lo:[1,0,0]"
        : "=&v"(a)
        : "v"(AR), "v"(AIt), "v"(p), "v"(BRt), "v"(q), "v"(BI));
    asm("v_pk_mul_f16 %0, %1, %5\n\t"
        "v_pk_fma_f16 %0, %2, %5, %0 op_sel:[0,1,0] op_sel_hi:[1,0,1] neg_hi:[1,0,0]\n\t"
        "v_pk_fma_f16 %0, %4, %3, %0 neg_lo:[1,0,0] neg_hi:[1,0,0]\n\t"
        "v_pk_fma_f16 %0, %6, %3, %0 op_sel:[0,1,0] op_sel_hi:[1,0,1] neg_lo:[1,0,0]"
        : "=&v"(b)
        : "v"(AR), "v"(AIt), "v"(p), "v"(BRt), "v"(q), "v"(BI));
    np_ = a; nq_ = b;
}

// Fused U = Rz(t2)Ry(t1)Rz(t0)Rx(enc), enc = 2*atan(x).
__global__ __launch_bounds__(512)
void precompute_kernel(const float* __restrict__ X, const float* __restrict__ Wt,
                       const float* __restrict__ Bs, uint4* __restrict__ Ug,
                       float* __restrict__ out)
{
    int id = blockIdx.x * 512 + threadIdx.x;
    if (id >= 512 * 64) return;
    int b = id >> 6, lw = id & 63, l = lw >> 4, w = lw & 15;
    float x  = X[b * 16 + w];
    float ce = 1.0f / sqrtf(1.0f + x * x);
    float se = x * ce;
    float t0 = 0.5f * Wt[(l * 16 + w) * 3 + 0];
    float t1 = 0.5f * Wt[(l * 16 + w) * 3 + 1];
    float t2 = 0.5f * Wt[(l * 16 + w) * 3 + 2];
    float c1 = cosf(t1), s1 = sinf(t1);
    float ca = cosf(t0 + t2), sa = sinf(t0 + t2);
    float cb = cosf(t2 - t0), sb = sinf(t2 - t0);
    float2 W00 = make_float2( c1 * ca, -c1 * sa);
    float2 W01 = make_float2(-s1 * cb,  s1 * sb);
    float2 a  = make_float2(W00.x * ce + W01.y * se, W00.y * ce - W01.x * se);
    float2 bb = make_float2(W00.y * se + W01.x * ce, -W00.x * se + W01.y * ce);
    uint4 o;
    o.x = pkh2(a.x,  a.x);
    o.y = pkh2(a.y,  a.y);
    o.z = pkh2(bb.x, bb.x);
    o.w = pkh2(bb.y, bb.y);
    Ug[id] = o;
    if (lw == 0) out[b] = Bs[0];
}

// Pass P of the compile-time schedule.
template <int P>
__global__ __launch_bounds__(256, 8)
void pass_kernel(const uint4* __restrict__ Ug, unsigned* __restrict__ state,
                 float* __restrict__ out)
{
    static constexpr PassMeta M = SCHED.pms[P];
    constexpr int NP   = SCHED.np;
    constexpr int MODE = (P == 0) ? 0 : ((P == NP - 1) ? 2 : 1);

    __shared__ __align__(16) unsigned amp[4096];   // 16 KiB
    __shared__ uint4 coef[64];
    const int tid = threadIdx.x;
    const int bb  = blockIdx.x >> 4;
    const unsigned c = blockIdx.x & 15u;
    const size_t base = (size_t)bb << 16;
    if (tid < 64) coef[tid] = Ug[(size_t)bb * 64 + tid];

    auto expand = [&](unsigned x) -> unsigned {   // gaps ascending, all >= 8
        #pragma unroll
        for (int k = 0; k < 4; ++k) {
            const unsigned g = M.gap[k];
            x = ((x >> g) << (g + 1)) | (x & ((1u << g) - 1u)) | (((c >> k) & 1u) << g);
        }
        return x;
    };

    if constexpr (MODE == 0) {
        __syncthreads();   // coef ready
        if (tid == 0) {
            float2 kv = make_float2(1.f, 0.f);
            #pragma unroll
            for (int t = 0; t < 4; ++t) {
                uint4 u = coef[M.nlw[t]];
                float ar = (float)bch2(u.x).x, ai = (float)bch2(u.y).x;
                float br = (float)bch2(u.z).x, bi = (float)bch2(u.w).x;
                float2 col = ((c >> t) & 1u) ? make_float2(-br, bi)
                                             : make_float2(ar, ai);
                kv = cmul2(kv, col);
            }
            amp[0] = pkh2(kv.x, kv.y);
        }
        __syncthreads();
        #pragma unroll
        for (int s = 0; s < 12; ++s) {
            const int n = 1 << s;
            uint4 cf = coef[M.wire_of_bit[s]];
            const h2 AR2  = bch2(cf.x);
            const h2 AIpm = h2x(bch2(cf.y), 0x00008000u);
            const h2 BRn  = h2x(bch2(cf.z), 0x80008000u);
            const h2 BIpm = h2x(bch2(cf.w), 0x00008000u);
            for (int i = tid; i < n; i += 256) {
                h2 a = bch2(amp[i]);
                h2 sw = a.yx;
                amp[i + n] = __builtin_bit_cast(unsigned, pkfma(BRn, a, BIpm * sw));
                amp[i]     = __builtin_bit_cast(unsigned, pkfma(AR2, a, AIpm * sw));
            }
            __syncthreads();
        }
    } else {
        #pragma unroll
        for (int it = 0; it < 4; ++it) {
            unsigned u = (unsigned)(tid + it * 256) * 4u;
            unsigned a = expand(u);
            uint4 v = *reinterpret_cast<const uint4*>(state + base + a);
            *reinterpret_cast<uint4*>(&amp[u]) = v;
        }
        __syncthreads();
    }

    #pragma unroll
    for (int ci = 0; ci < M.nbundles; ++ci) {
        unsigned r = (unsigned)tid;
        #pragma unroll
        for (int k = 0; k < 4; ++k) {
            const unsigned p = M.bd[ci].piv[k];
            r = ((r >> p) << (p + 1)) | (r & ((1u << p) - 1u));
        }
        const unsigned rb = r << 2;
        unsigned a_[16];
        #pragma unroll
        for (int t = 0; t < 16; ++t)
            a_[t] = *(const unsigned*)((const char*)amp +
                     (rb ^ ((unsigned)M.bd[ci].voff[t] << 2)));
        #pragma unroll
        for (int g = 0; g < 4; ++g) {
            if (M.bd[ci].gidx[g] == 0xFF) continue;
            const uint4 cf = coef[M.bd[ci].gidx[g]];
            const unsigned par = ((unsigned)__popc(r & (unsigned)M.bd[ci].row[g]) +
                                  (unsigned)__popc((unsigned)M.bd[ci].nl[g] & c)) & 1u;
            const unsigned gm = par ? 0x80008000u : 0u;
            const unsigned AR  = cf.x;
            const unsigned BI  = cf.w;
            const unsigned AIg = cf.y ^ gm;
            const unsigned BRg = cf.z ^ gm;
            const unsigned AIf = AIg ^ 0x80008000u;
            const unsigned BRf = BRg ^ 0x80008000u;
            #pragma unroll
            for (int t = 0; t < 16; ++t) {
                if (t & (1 << g)) continue;
                const int t2 = t | (1 << g);
                const bool FB = ((M.bd[ci].flip[g] >> t) & 1u) != 0;  // compile-time
                unsigned np_, nq_;
                pair_rot(np_, nq_, a_[t], a_[t2], AR,
                         FB ? AIf : AIg, FB ? BRf : BRg, BI);
                a_[t] = np_; a_[t2] = nq_;
            }
        }
        if (MODE == 2 && ci == M.nbundles - 1) {
            float acc = 0.f;
            const unsigned sb = (((unsigned)__popc(r & (unsigned)M.meas_row) +
                                  (unsigned)__popc((unsigned)M.meas_nl & c)) & 1u) << 31;
            #pragma unroll
            for (int t = 0; t < 16; ++t) {
                h2 a = bch2(a_[t]);
                float vr = (float)a.x, vi = (float)a.y;
                float pr = __builtin_fmaf(vr, vr, vi * vi);
                const unsigned st =
                    __builtin_parity((unsigned)(M.bd[ci].voff[t] & M.meas_row))
                        ? 0x80000000u : 0u;   // compile-time
                acc += xorf(pr, sb ^ st);
            }
            for (int off = 32; off > 0; off >>= 1) acc += __shfl_down(acc, off, 64);
            if ((tid & 63) == 0) atomicAdd(&out[bb], acc);
            return;
        }
        #pragma unroll
        for (int t = 0; t < 16; ++t)
            *(unsigned*)((char*)amp + (rb ^ ((unsigned)M.bd[ci].voff[t] << 2))) = a_[t];
        __syncthreads();
    }

    if constexpr (MODE == 2) {
        float acc = 0.f;
        const unsigned mcp = (unsigned)(__popc((unsigned)M.meas_nl & c) & 1);
        for (int k = 0; k < 16; ++k) {
            unsigned u = (unsigned)(tid + k * 256);
            h2 a = bch2(amp[u]);
            float vr = (float)a.x, vi = (float)a.y;
            float pr = __builtin_fmaf(vr, vr, vi * vi);
            acc += (((unsigned)__popc(u & (unsigned)M.meas_row) & 1u) ^ mcp)
                 ? -pr : pr;
        }
        for (int off = 32; off > 0; off >>= 1) acc += __shfl_down(acc, off, 64);
        if ((tid & 63) == 0) atomicAdd(&out[bb], acc);
    } else {
        #pragma unroll
        for (int it = 0; it < 4; ++it) {
            unsigned u = (unsigned)(tid + it * 256) * 4u;
            unsigned ad = expand(u);
            uint4 v = *reinterpret_cast<const uint4*>(&amp[u]);
            *reinterpret_cast<uint4*>(state + base + ad) = v;
        }
    }
}

extern "C" void kernel_launch(void* const* d_in, const int* in_sizes, int n_in,
                              void* d_out, int out_size, void* d_ws, size_t ws_size,
                              hipStream_t stream)
{
    const float* X  = (const float*)d_in[0];
    const float* Wt = (const float*)d_in[1];
    const float* Bs = (const float*)d_in[2];
    float* out = (float*)d_out;

    const size_t UG_BYTES = (size_t)512 * 64 * sizeof(uint4);  // 512 KiB
    uint4*    Ug    = (uint4*)d_ws;
    unsigned* state = (unsigned*)((char*)d_ws + UG_BYTES);
    size_t avail = ws_size > UG_BYTES ? ws_size - UG_BYTES : 0;
    int group = 1;   // fp16 state: 256 KiB per batch element
    while (group < 512 && (size_t)(group * 2) * 262144ull <= avail)
        group <<= 1;
    const int ngroups = 512 / group;

    constexpr int NP = SCHED.np;

    precompute_kernel<<<dim3(64), dim3(512), 0, stream>>>(X, Wt, Bs, Ug, out);
    for (int g = 0; g < ngroups; ++g) {
        const uint4* ug = Ug + (size_t)g * group * 64;
        float* og = out + (size_t)g * group;
        dim3 grid((unsigned)(group << 4));
        for (int p = 0; p < NP; ++p) {
            switch (p) {
            case 0: pass_kernel<0><<<grid, dim3(256), 0, stream>>>(ug, state, og); break;
            case 1: pass_kernel<1><<<grid, dim3(256), 0, stream>>>(ug, state, og); break;
            case 2: pass_kernel<2><<<grid, dim3(256), 0, stream>>>(ug, state, og); break;
            case 3: pass_kernel<3><<<grid, dim3(256), 0, stream>>>(ug, state, og); break;
            case 4: pass_kernel<4><<<grid, dim3(256), 0, stream>>>(ug, state, og); break;
            case 5: pass_kernel<5><<<grid, dim3(256), 0, stream>>>(ug, state, og); break;
            case 6: pass_kernel<6><<<grid, dim3(256), 0, stream>>>(ug, state, og); break;
            case 7: pass_kernel<7><<<grid, dim3(256), 0, stream>>>(ug, state, og); break;
            }
        }
    }

    (void)in_sizes; (void)n_in; (void)out_size; (void)ws_size;
}